// Round 1
// baseline (216.045 us; speedup 1.0000x reference)
//
#include <hip/hip_runtime.h>
#include <math.h>

#define KS   5
#define K2   25
#define DYN  32
#define CTOT 64
#define BB   4
#define HH   256
#define WW   256

__global__ __launch_bounds__(256, 4)
void local_attn_kernel(const float* __restrict__ x,
                       const float* __restrict__ kern,
                       float* __restrict__ out)
{
    __shared__ float kw[K2];
    const int tid = threadIdx.x;
    if (tid < K2) kw[tid] = kern[tid] * (1.0f / KS);
    __syncthreads();

    const int w = tid;            // 0..255 (block = one image row)
    const int h = blockIdx.x;     // 0..255
    const int b = blockIdx.y;     // 0..3

    // Clamped row/col indices + validity (zero-padding semantics)
    int  rowi[KS]; bool rowv[KS];
    int  coli[KS]; bool colv[KS];
#pragma unroll
    for (int i = 0; i < KS; ++i) {
        int r = h + i - 2;
        rowv[i] = (unsigned)r < (unsigned)HH;
        rowi[i] = min(max(r, 0), HH - 1);
        int c = w + i - 2;
        colv[i] = (unsigned)c < (unsigned)WW;
        coli[i] = min(max(c, 0), WW - 1);
    }

    const size_t plane = (size_t)HH * WW;
    const float* xb = x + (size_t)b * CTOT * plane;
    const int    pix = h * WW + w;

    float s[K2];
#pragma unroll
    for (int k = 0; k < K2; ++k) s[k] = 0.0f;

    // ---- scores: dot over static channels [32,64) of tap vs center ----
#pragma unroll 1
    for (int c = DYN; c < CTOT; ++c) {
        const float* xc = xb + (size_t)c * plane;
        const float  center = xc[pix];
#pragma unroll
        for (int i = 0; i < KS; ++i) {
            const float* xr = xc + rowi[i] * WW;
#pragma unroll
            for (int j = 0; j < KS; ++j) {
                s[i * KS + j] = fmaf(xr[coli[j]], center, s[i * KS + j]);
            }
        }
    }

    // ---- scale by kernel/5, zero invalid taps, softmax over 25 taps ----
    float m = -INFINITY;
#pragma unroll
    for (int k = 0; k < K2; ++k) {
        const int i = k / KS, j = k % KS;
        float sc = (rowv[i] && colv[j]) ? s[k] * kw[k] : 0.0f;
        s[k] = sc;
        m = fmaxf(m, sc);
    }
    float sum = 0.0f;
#pragma unroll
    for (int k = 0; k < K2; ++k) {
        float e = __expf(s[k] - m);
        s[k] = e;
        sum += e;
    }
    const float inv = 1.0f / sum;
#pragma unroll
    for (int k = 0; k < K2; ++k) {
        const int i = k / KS, j = k % KS;
        // invalid taps: zero weight so clamped (garbage) loads contribute 0,
        // but they already contributed exp(0-m) to the denominator (correct).
        s[k] = (rowv[i] && colv[j]) ? s[k] * inv : 0.0f;
    }

    // ---- output: weighted sum of dynamic channels [0,32) ----
    float* ob = out + (size_t)b * DYN * plane;
#pragma unroll 1
    for (int c = 0; c < DYN; ++c) {
        const float* xc = xb + (size_t)c * plane;
        float acc = 0.0f;
#pragma unroll
        for (int i = 0; i < KS; ++i) {
            const float* xr = xc + rowi[i] * WW;
#pragma unroll
            for (int j = 0; j < KS; ++j) {
                acc = fmaf(xr[coli[j]], s[i * KS + j], acc);
            }
        }
        ob[c * plane + pix] = acc;
    }
}

extern "C" void kernel_launch(void* const* d_in, const int* in_sizes, int n_in,
                              void* d_out, int out_size, void* d_ws, size_t ws_size,
                              hipStream_t stream) {
    const float* x    = (const float*)d_in[0];
    const float* kern = (const float*)d_in[1];
    float*       out  = (float*)d_out;

    dim3 grid(HH, BB, 1);
    dim3 block(WW, 1, 1);
    hipLaunchKernelGGL(local_attn_kernel, grid, block, 0, stream, x, kern, out);
}

// Round 2
// 158.358 us; speedup vs baseline: 1.3643x; 1.3643x over previous
//
#include <hip/hip_runtime.h>
#include <math.h>

#define KS   5
#define K2   25
#define DYN  32
#define CTOT 64
#define BB   4
#define HH   256
#define WW   256
#define PLANE (HH * WW)

// One thread computes 4 consecutive pixels (w0 = 4*lane64).
// Block: 256 threads = 4 rows x 64 pixel-groups. Grid: (H/4, B) = 256 blocks.
// Per channel, the 4 pixels' windows (cols w0-2..w0+5) are covered by 3
// aligned float4 loads per row x 5 rows = 15 dwordx4 serving 100 tap-FMAs.
__global__ __launch_bounds__(256, 1)
void local_attn_kernel(const float* __restrict__ x,
                       const float* __restrict__ kern,
                       float* __restrict__ out)
{
    __shared__ float kw[K2];
    const int tid = threadIdx.x;
    if (tid < K2) kw[tid] = kern[tid] * (1.0f / KS);
    __syncthreads();

    const int tx = tid & 63;        // pixel-group along W
    const int ty = tid >> 6;        // row within block (0..3)
    const int w0 = tx << 2;         // first pixel column of this thread
    const int h  = blockIdx.x * 4 + ty;
    const int b  = blockIdx.y;

    // Clamped row indices + validity (zero-padding semantics)
    int rowi[KS]; bool rowv[KS];
#pragma unroll
    for (int i = 0; i < KS; ++i) {
        int r = h + i - 2;
        rowv[i] = (unsigned)r < (unsigned)HH;
        rowi[i] = min(max(r, 0), HH - 1);
    }
    // Column validity for window offset m (tap col = w0 + m - 2, m = p+j in 0..8)
    bool colv[9];
#pragma unroll
    for (int m = 0; m < 9; ++m) colv[m] = (unsigned)(w0 + m - 2) < (unsigned)WW;

    // float4-block indices (clamped; garbage is masked at score/weight level)
    const int qm1 = max(tx - 1, 0);
    const int qp1 = min(tx + 1, 63);

    const float* xb = x + (size_t)b * CTOT * PLANE;

    float s[4][K2];
#pragma unroll
    for (int p = 0; p < 4; ++p)
#pragma unroll
        for (int k = 0; k < K2; ++k) s[p][k] = 0.0f;

    // ---- score phase: dot(tap, center) over static channels [32,64) ----
#pragma unroll 2
    for (int c = DYN; c < CTOT; ++c) {
        const float* xc = xb + c * PLANE;
        float w[KS][12];
#pragma unroll
        for (int i = 0; i < KS; ++i) {
            const float4* rb = (const float4*)(xc + rowi[i] * WW);
            float4 a = rb[qm1], bq = rb[tx], cq = rb[qp1];
            w[i][0] = a.x;  w[i][1] = a.y;  w[i][2]  = a.z;  w[i][3]  = a.w;
            w[i][4] = bq.x; w[i][5] = bq.y; w[i][6]  = bq.z; w[i][7]  = bq.w;
            w[i][8] = cq.x; w[i][9] = cq.y; w[i][10] = cq.z; w[i][11] = cq.w;
        }
        // center pixel values: col w0+p -> window index p+4 in row i=2 (always valid data)
        float ctr[4];
#pragma unroll
        for (int p = 0; p < 4; ++p) ctr[p] = w[2][p + 4];
#pragma unroll
        for (int p = 0; p < 4; ++p)
#pragma unroll
            for (int i = 0; i < KS; ++i)
#pragma unroll
                for (int j = 0; j < KS; ++j)
                    s[p][i * KS + j] = fmaf(w[i][p + j + 2], ctr[p], s[p][i * KS + j]);
    }

    // ---- softmax over 25 taps per pixel (masked taps are exactly 0 pre-softmax,
    //      participate in denominator, then get zero weight) ----
#pragma unroll
    for (int p = 0; p < 4; ++p) {
        float m = -INFINITY;
#pragma unroll
        for (int i = 0; i < KS; ++i)
#pragma unroll
            for (int j = 0; j < KS; ++j) {
                const int k = i * KS + j;
                float v = (rowv[i] && colv[p + j]) ? s[p][k] * kw[k] : 0.0f;
                s[p][k] = v;
                m = fmaxf(m, v);
            }
        float sum = 0.0f;
#pragma unroll
        for (int k = 0; k < K2; ++k) {
            float e = __expf(s[p][k] - m);
            s[p][k] = e;
            sum += e;
        }
        const float inv = 1.0f / sum;
#pragma unroll
        for (int i = 0; i < KS; ++i)
#pragma unroll
            for (int j = 0; j < KS; ++j) {
                const int k = i * KS + j;
                s[p][k] = (rowv[i] && colv[p + j]) ? s[p][k] * inv : 0.0f;
            }
    }

    // ---- output phase: weighted sum of dynamic channels [0,32) ----
    float* ob = out + (size_t)b * DYN * PLANE + h * WW + w0;
#pragma unroll 2
    for (int c = 0; c < DYN; ++c) {
        const float* xc = xb + c * PLANE;
        float w[KS][12];
#pragma unroll
        for (int i = 0; i < KS; ++i) {
            const float4* rb = (const float4*)(xc + rowi[i] * WW);
            float4 a = rb[qm1], bq = rb[tx], cq = rb[qp1];
            w[i][0] = a.x;  w[i][1] = a.y;  w[i][2]  = a.z;  w[i][3]  = a.w;
            w[i][4] = bq.x; w[i][5] = bq.y; w[i][6]  = bq.z; w[i][7]  = bq.w;
            w[i][8] = cq.x; w[i][9] = cq.y; w[i][10] = cq.z; w[i][11] = cq.w;
        }
        float4 acc = make_float4(0.f, 0.f, 0.f, 0.f);
        float* ap = &acc.x;
#pragma unroll
        for (int p = 0; p < 4; ++p) {
            float a = 0.0f;
#pragma unroll
            for (int i = 0; i < KS; ++i)
#pragma unroll
                for (int j = 0; j < KS; ++j)
                    a = fmaf(w[i][p + j + 2], s[p][i * KS + j], a);
            ap[p] = a;
        }
        *(float4*)(ob + c * PLANE) = acc;
    }
}

extern "C" void kernel_launch(void* const* d_in, const int* in_sizes, int n_in,
                              void* d_out, int out_size, void* d_ws, size_t ws_size,
                              hipStream_t stream) {
    const float* x    = (const float*)d_in[0];
    const float* kern = (const float*)d_in[1];
    float*       out  = (float*)d_out;

    dim3 grid(HH / 4, BB, 1);
    dim3 block(256, 1, 1);
    hipLaunchKernelGGL(local_attn_kernel, grid, block, 0, stream, x, kern, out);
}

// Round 3
// 152.386 us; speedup vs baseline: 1.4177x; 1.0392x over previous
//
#include <hip/hip_runtime.h>
#include <math.h>

#define KS   5
#define K2   25
#define DYN  32
#define CTOT 64
#define BB   4
#define HH   256
#define WW   256
#define PLANE (HH * WW)

// 2 pixels/thread (horizontal pair, w0 = 2*gx). Block: 256 threads =
// 2 rows x 128 pixel-pairs. Grid: (H/2, B) = 512 blocks -> 2 blocks/CU,
// 8 waves/CU (2x the TLP of the 4px/thread version).
// Per channel: 5 rows x 3 aligned float2 loads = 15 dwordx2 serving 50 FMAs.
__global__ __launch_bounds__(256, 2)
void local_attn_kernel(const float* __restrict__ x,
                       const float* __restrict__ kern,
                       float* __restrict__ out)
{
    __shared__ float kw[K2];
    const int tid = threadIdx.x;
    if (tid < K2) kw[tid] = kern[tid] * (1.0f / KS);
    __syncthreads();

    const int gx = tid & 127;       // pixel-pair index along W
    const int ty = tid >> 7;        // row within block (0..1)
    const int w0 = gx << 1;         // first pixel column
    const int h  = blockIdx.x * 2 + ty;
    const int b  = blockIdx.y;

    // Clamped row indices + validity (zero-padding semantics)
    int rowi[KS]; bool rowv[KS];
#pragma unroll
    for (int i = 0; i < KS; ++i) {
        int r = h + i - 2;
        rowv[i] = (unsigned)r < (unsigned)HH;
        rowi[i] = min(max(r, 0), HH - 1);
    }
    // Window col m (0..5) -> image col w0 + m - 2 ; tap (p,j) uses m = p+j
    bool colv[6];
#pragma unroll
    for (int m = 0; m < 6; ++m) colv[m] = (unsigned)(w0 + m - 2) < (unsigned)WW;

    // float2-block indices (clamped; garbage masked at score/weight level)
    const int gm1 = max(gx - 1, 0);
    const int gp1 = min(gx + 1, 127);

    const float* xb = x + (size_t)b * CTOT * PLANE;

    float s[2][K2];
#pragma unroll
    for (int p = 0; p < 2; ++p)
#pragma unroll
        for (int k = 0; k < K2; ++k) s[p][k] = 0.0f;

    // ---- score phase: dot(tap, center) over static channels [32,64) ----
#pragma unroll 2
    for (int c = DYN; c < CTOT; ++c) {
        const float* xc = xb + c * PLANE;
        float w[KS][6];
#pragma unroll
        for (int i = 0; i < KS; ++i) {
            const float2* rb = (const float2*)(xc + rowi[i] * WW);
            float2 a = rb[gm1], bq = rb[gx], cq = rb[gp1];
            w[i][0] = a.x;  w[i][1] = a.y;
            w[i][2] = bq.x; w[i][3] = bq.y;
            w[i][4] = cq.x; w[i][5] = cq.y;
        }
        float ctr[2];
#pragma unroll
        for (int p = 0; p < 2; ++p) ctr[p] = w[2][p + 2];  // col w0+p, row h
#pragma unroll
        for (int p = 0; p < 2; ++p)
#pragma unroll
            for (int i = 0; i < KS; ++i)
#pragma unroll
                for (int j = 0; j < KS; ++j)
                    s[p][i * KS + j] = fmaf(w[i][p + j], ctr[p], s[p][i * KS + j]);
    }

    // ---- softmax over 25 taps (masked taps exactly 0 pre-softmax; they
    //      stay in the denominator; weight zeroed afterwards) ----
#pragma unroll
    for (int p = 0; p < 2; ++p) {
        float m = -INFINITY;
#pragma unroll
        for (int i = 0; i < KS; ++i)
#pragma unroll
            for (int j = 0; j < KS; ++j) {
                const int k = i * KS + j;
                float v = (rowv[i] && colv[p + j]) ? s[p][k] * kw[k] : 0.0f;
                s[p][k] = v;
                m = fmaxf(m, v);
            }
        float sum = 0.0f;
#pragma unroll
        for (int k = 0; k < K2; ++k) {
            float e = __expf(s[p][k] - m);
            s[p][k] = e;
            sum += e;
        }
        const float inv = 1.0f / sum;
#pragma unroll
        for (int i = 0; i < KS; ++i)
#pragma unroll
            for (int j = 0; j < KS; ++j) {
                const int k = i * KS + j;
                s[p][k] = (rowv[i] && colv[p + j]) ? s[p][k] * inv : 0.0f;
            }
    }

    // ---- output phase: weighted sum of dynamic channels [0,32) ----
    float* ob = out + (size_t)b * DYN * PLANE + h * WW + w0;
#pragma unroll 4
    for (int c = 0; c < DYN; ++c) {
        const float* xc = xb + c * PLANE;
        float w[KS][6];
#pragma unroll
        for (int i = 0; i < KS; ++i) {
            const float2* rb = (const float2*)(xc + rowi[i] * WW);
            float2 a = rb[gm1], bq = rb[gx], cq = rb[gp1];
            w[i][0] = a.x;  w[i][1] = a.y;
            w[i][2] = bq.x; w[i][3] = bq.y;
            w[i][4] = cq.x; w[i][5] = cq.y;
        }
        float2 acc;
        float* ap = &acc.x;
#pragma unroll
        for (int p = 0; p < 2; ++p) {
            float a = 0.0f;
#pragma unroll
            for (int i = 0; i < KS; ++i)
#pragma unroll
                for (int j = 0; j < KS; ++j)
                    a = fmaf(w[i][p + j], s[p][i * KS + j], a);
            ap[p] = a;
        }
        *(float2*)(ob + c * PLANE) = acc;
    }
}

extern "C" void kernel_launch(void* const* d_in, const int* in_sizes, int n_in,
                              void* d_out, int out_size, void* d_ws, size_t ws_size,
                              hipStream_t stream) {
    const float* x    = (const float*)d_in[0];
    const float* kern = (const float*)d_in[1];
    float*       out  = (float*)d_out;

    dim3 grid(HH / 2, BB, 1);
    dim3 block(256, 1, 1);
    hipLaunchKernelGGL(local_attn_kernel, grid, block, 0, stream, x, kern, out);
}

// Round 4
// 126.376 us; speedup vs baseline: 1.7095x; 1.2058x over previous
//
#include <hip/hip_runtime.h>
#include <math.h>

#define KS   5
#define K2   25
#define DYN  32
#define CTOT 64
#define BB   4
#define HH   256
#define WW   256
#define PLANE (HH * WW)
#define LROW 264                 // floats per LDS row: 4 halo (2+2) + 256 + pad
#define LR   7                   // 6 data rows + 1 dump row (for OOB staging)
#define LBUF (LR * LROW)

// Block = 2 output rows x 256 cols (512 px), 256 threads, 2 px/thread.
// Per channel: stage 6 rows (2 + 4 halo) into LDS, double-buffered; compute
// windows from LDS. LDS halo/dump pre-zeroed => zero-padding is implicit,
// no boundary masks anywhere (OOB taps score exactly 0, matching reference).
__global__ __launch_bounds__(256, 2)
void local_attn_kernel(const float* __restrict__ x,
                       const float* __restrict__ kern,
                       float* __restrict__ out)
{
    __shared__ float kw[K2];
    __shared__ float lds[2][LR][LROW];

    const int tid = threadIdx.x;
    // zero LDS: halo cols, dump row, and never-staged OOB rows stay 0 forever
    for (int i = tid; i < 2 * LBUF; i += 256) ((float*)lds)[i] = 0.0f;
    if (tid < K2) kw[tid] = kern[tid] * (1.0f / KS);

    const int gx = tid & 127;       // pixel-pair along W
    const int ty = tid >> 7;        // output row within block (0/1)
    const int w0 = gx << 1;
    const int h0 = blockIdx.x * 2;
    const int h  = h0 + ty;
    const int b  = blockIdx.y;

    const float* xb = x + (size_t)b * CTOT * PLANE;

    // staging map: idx = tid + k*256 -> buffer row idx>>7 (0..5), col-pair idx&127
    int goff[3], loff[3];
#pragma unroll
    for (int k = 0; k < 3; ++k) {
        const int idx  = tid + (k << 8);
        const int row  = idx >> 7;          // 0..5
        const int col2 = idx & 127;
        const int r    = h0 - 2 + row;      // image row
        const bool v   = (unsigned)r < (unsigned)HH;
        goff[k] = min(max(r, 0), HH - 1) * WW + (col2 << 1);
        loff[k] = (v ? row : 6) * LROW + 2 + (col2 << 1);   // OOB -> dump row
    }

    __syncthreads();   // zero-init visible before first stage

    float s[2][K2];
#pragma unroll
    for (int p = 0; p < 2; ++p)
#pragma unroll
        for (int k = 0; k < K2; ++k) s[p][k] = 0.0f;

    // ================= score phase: channels [32,64) =================
    {
        const float* xc = xb + DYN * PLANE;
        float2 p0 = *(const float2*)(xc + goff[0]);
        float2 p1 = *(const float2*)(xc + goff[1]);
        float2 p2 = *(const float2*)(xc + goff[2]);
        float* l0 = &lds[0][0][0];
        *(float2*)(l0 + loff[0]) = p0;
        *(float2*)(l0 + loff[1]) = p1;
        *(float2*)(l0 + loff[2]) = p2;
    }
    __syncthreads();

#pragma unroll 1
    for (int c = DYN; c < CTOT; ++c) {
        const int pb = (c - DYN) & 1;
        const bool have = (c + 1 < CTOT);
        float2 n0, n1, n2;
        if (have) {
            const float* xn = xb + (c + 1) * PLANE;
            n0 = *(const float2*)(xn + goff[0]);
            n1 = *(const float2*)(xn + goff[1]);
            n2 = *(const float2*)(xn + goff[2]);
        }
        const float* base = &lds[pb][ty][0];   // window row i at base + i*LROW
        // row i=2 first (holds the center pixels)
        float ctr0, ctr1;
        {
            const float* rp = base + 2 * LROW + w0;
            float2 q0 = *(const float2*)(rp);
            float2 q1 = *(const float2*)(rp + 2);
            float2 q2 = *(const float2*)(rp + 4);
            float wr[6] = {q0.x, q0.y, q1.x, q1.y, q2.x, q2.y};
            ctr0 = wr[2]; ctr1 = wr[3];
#pragma unroll
            for (int j = 0; j < KS; ++j) {
                s[0][2 * KS + j] = fmaf(wr[j],     ctr0, s[0][2 * KS + j]);
                s[1][2 * KS + j] = fmaf(wr[j + 1], ctr1, s[1][2 * KS + j]);
            }
        }
#pragma unroll
        for (int i = 0; i < KS; ++i) {
            if (i == 2) continue;
            const float* rp = base + i * LROW + w0;
            float2 q0 = *(const float2*)(rp);
            float2 q1 = *(const float2*)(rp + 2);
            float2 q2 = *(const float2*)(rp + 4);
            float wr[6] = {q0.x, q0.y, q1.x, q1.y, q2.x, q2.y};
#pragma unroll
            for (int j = 0; j < KS; ++j) {
                s[0][i * KS + j] = fmaf(wr[j],     ctr0, s[0][i * KS + j]);
                s[1][i * KS + j] = fmaf(wr[j + 1], ctr1, s[1][i * KS + j]);
            }
        }
        if (have) {
            float* ln = &lds[pb ^ 1][0][0];
            *(float2*)(ln + loff[0]) = n0;
            *(float2*)(ln + loff[1]) = n1;
            *(float2*)(ln + loff[2]) = n2;
        }
        __syncthreads();
    }

    // ================= softmax over 25 taps (no masks needed) =========
#pragma unroll
    for (int p = 0; p < 2; ++p) {
        float m = -INFINITY;
#pragma unroll
        for (int k = 0; k < K2; ++k) {
            float v = s[p][k] * kw[k];
            s[p][k] = v;
            m = fmaxf(m, v);
        }
        float sum = 0.0f;
#pragma unroll
        for (int k = 0; k < K2; ++k) {
            float e = __expf(s[p][k] - m);
            s[p][k] = e;
            sum += e;
        }
        const float inv = 1.0f / sum;
#pragma unroll
        for (int k = 0; k < K2; ++k) s[p][k] *= inv;
    }

    // ================= output phase: channels [0,32) ==================
    {
        const float* xc = xb;   // c = 0
        float2 p0 = *(const float2*)(xc + goff[0]);
        float2 p1 = *(const float2*)(xc + goff[1]);
        float2 p2 = *(const float2*)(xc + goff[2]);
        float* l0 = &lds[0][0][0];
        *(float2*)(l0 + loff[0]) = p0;
        *(float2*)(l0 + loff[1]) = p1;
        *(float2*)(l0 + loff[2]) = p2;
    }
    __syncthreads();

    float* ob = out + (size_t)b * DYN * PLANE + h * WW + w0;
#pragma unroll 1
    for (int c = 0; c < DYN; ++c) {
        const int pb = c & 1;
        const bool have = (c + 1 < DYN);
        float2 n0, n1, n2;
        if (have) {
            const float* xn = xb + (c + 1) * PLANE;
            n0 = *(const float2*)(xn + goff[0]);
            n1 = *(const float2*)(xn + goff[1]);
            n2 = *(const float2*)(xn + goff[2]);
        }
        const float* base = &lds[pb][ty][0];
        float acc0 = 0.0f, acc1 = 0.0f;
#pragma unroll
        for (int i = 0; i < KS; ++i) {
            const float* rp = base + i * LROW + w0;
            float2 q0 = *(const float2*)(rp);
            float2 q1 = *(const float2*)(rp + 2);
            float2 q2 = *(const float2*)(rp + 4);
            float wr[6] = {q0.x, q0.y, q1.x, q1.y, q2.x, q2.y};
#pragma unroll
            for (int j = 0; j < KS; ++j) {
                acc0 = fmaf(wr[j],     s[0][i * KS + j], acc0);
                acc1 = fmaf(wr[j + 1], s[1][i * KS + j], acc1);
            }
        }
        if (have) {
            float* ln = &lds[pb ^ 1][0][0];
            *(float2*)(ln + loff[0]) = n0;
            *(float2*)(ln + loff[1]) = n1;
            *(float2*)(ln + loff[2]) = n2;
        }
        float2 o; o.x = acc0; o.y = acc1;
        *(float2*)(ob + c * PLANE) = o;
        __syncthreads();
    }
}

extern "C" void kernel_launch(void* const* d_in, const int* in_sizes, int n_in,
                              void* d_out, int out_size, void* d_ws, size_t ws_size,
                              hipStream_t stream) {
    const float* x    = (const float*)d_in[0];
    const float* kern = (const float*)d_in[1];
    float*       out  = (float*)d_out;

    dim3 grid(HH / 2, BB, 1);
    dim3 block(256, 1, 1);
    hipLaunchKernelGGL(local_attn_kernel, grid, block, 0, stream, x, kern, out);
}